// Round 9
// baseline (133.436 us; speedup 1.0000x reference)
//
#include <hip/hip_runtime.h>
#include <math.h>

#define NXv 128
#define NYv 128
#define NZv 128
#define NVOX (NXv * NYv * NZv)
#define RPB  64    // rays per block (lane = ray in compute phase)
#define TSEG 63    // segments per LDS tile (loads TSEG+1 = 64 t-values/ray)

// Lane-per-ray tiled kernel, register-prefetch pipeline + phase-split gather
// batch (R9).
//  * tvals bits are AUTHORITATIVE: R6 proved on-the-fly recompute differs at
//    the ulp level (XLA divide != HW IEEE div bits) and flips knife-edge
//    floors. tvals must be read from memory.
//  * lane = ray (R7, 142->93us): consecutive rays differ only in detector v
//    -> volume gathers span 2-8 cache lines instead of 64 (R4/R5 floor).
//  * tvals coalescing via LDS transpose tile, stride 65 -> conflict-free.
//  * reg-prefetch of next tile before compute (R8, 93->84us).
//  * R9: compute phase split into {weights/offsets -> arrays} then {ALL 32
//    gathers back-to-back} then {accumulate}. R8's VGPR=48 proved the
//    compiler was chaining load->fma (4-8 gathers in flight, latency-bound
//    at VALUBusy 21%). Branchless select + clamped offsets (proven R5) make
//    every load unconditional. __launch_bounds__(256,4) caps VGPR at 128 ->
//    4 blocks/CU -> grid (2048) = 2x residency -> refill fixes the 46%
//    achieved-occupancy tail imbalance.
//
// NUMERICS (hard-won, rounds 1-8): x-segment midpoints land EXACTLY on
// floor() discontinuities. Golden ref is f32 numpy, SEPARATE mul-then-add.
// hipcc contracts a+tm*d into FMA -> absmax ~18.7 (threshold 1.25); __f*_rn
// are contractible (R2 == R1 bitwise); f64 mismatches (R3); recomputed t
// mismatches (R6). The asm VGPR pin on the product tm*d is what works
// (R4/R5/R7/R8 passed, absmax 0.0625). Do not remove. Keep contract(off).
// Invalid/garbage lanes: clamp floats BEFORE int cast (NaN -> -2 via fmaxf),
// clamp flat index into range, weight forced 0 -> deterministic (proven R5).
template <int BT>
__global__ __launch_bounds__(256, 4) void ct_batch(
    const float* __restrict__ vol,    // (B, NX, NY, NZ)
    const float* __restrict__ tvals,  // (R, S) sorted, +inf padded
    const float* __restrict__ Mm,     // (3,3)
    const float* __restrict__ bb,     // (3,)
    const float* __restrict__ src,    // (R,3)
    const float* __restrict__ dst,    // (R,3)
    float* __restrict__ out,          // (B, R)
    int R, int S)
{
#pragma clang fp contract(off)
    __shared__ float tile[RPB][TSEG + 2];   // 64 x 65: stride 65 -> conflict-free
    __shared__ float red[4][RPB][2];        // cross-sub reduction

    const float INF = __builtin_inff();
    const int t   = threadIdx.x;
    const int rr  = t & 63;        // compute role: ray within block
    const int sub = t >> 6;        // compute role: segment sub-range 0..3
    const int r0  = blockIdx.x * RPB;
    const int r   = r0 + rr;
    const bool active = (r < R);

    // --- per-ray geometry (verified R4/R5/R7/R8) ---
    float ax = 0, ay = 0, az = 0, dxx = 0, dyy = 0, dzz = 0, raylen = 0;
    if (active) {
        const float sx = src[r * 3 + 0], sy = src[r * 3 + 1], sz = src[r * 3 + 2];
        const float ex = dst[r * 3 + 0], ey = dst[r * 3 + 1], ez = dst[r * 3 + 2];
        const float M00 = Mm[0], M01 = Mm[1], M02 = Mm[2];
        const float M10 = Mm[3], M11 = Mm[4], M12 = Mm[5];
        const float M20 = Mm[6], M21 = Mm[7], M22 = Mm[8];
        ax = M00 * sx + M01 * sy + M02 * sz + bb[0];
        ay = M10 * sx + M11 * sy + M12 * sz + bb[1];
        az = M20 * sx + M21 * sy + M22 * sz + bb[2];
        const float vx = ex - sx, vy = ey - sy, vz = ez - sz;
        dxx = M00 * vx + M01 * vy + M02 * vz;
        dyy = M10 * vx + M11 * vy + M12 * vz;
        dzz = M20 * vx + M21 * vy + M22 * vz;
        raylen = sqrtf(vx * vx + vy * vy + vz * vz);
    }

    const int nseg  = S - 1;
    const int ntile = (nseg + TSEG - 1) / TSEG;
    float acc0 = 0.0f, acc1 = 0.0f;

    // staged registers: pf[p] = tvals[ray = r0+4p+sub][s0 + rr]
    float pf[16];
    {
        const int idx = rr;                      // tile 0: s0 = 0
#pragma unroll
        for (int p = 0; p < 16; ++p) {
            const int ray = r0 + p * 4 + sub;
            pf[p] = (ray < R && idx < S) ? tvals[(long)ray * S + idx] : INF;
        }
    }

    for (int tl = 0; tl < ntile; ++tl) {
        // --- stage-write: regs -> LDS (compiler inserts the vmcnt wait) ---
#pragma unroll
        for (int p = 0; p < 16; ++p)
            tile[p * 4 + sub][rr] = pf[p];

        // alive predicate from staged regs (tile-start values in rr==0
        // threads): sorted + INF tail -> block-uniform break. The
        // syncthreads_count doubles as the write->read barrier.
        bool pred = false;
        if (rr == 0) {
#pragma unroll
            for (int p = 0; p < 16; ++p) pred |= (pf[p] < INF);
        }
        const int alive = __syncthreads_count(pred);
        if (alive == 0) break;

        // --- prefetch next tile into regs (issued; consumed next iter) ---
        if (tl + 1 < ntile) {
            const int idx = (tl + 1) * TSEG + rr;
#pragma unroll
            for (int p = 0; p < 16; ++p) {
                const int ray = r0 + p * 4 + sub;
                pf[p] = (ray < R && idx < S) ? tvals[(long)ray * S + idx] : INF;
            }
        }

        // --- phase A: weights + clamped offsets for 16 segments (branchless) ---
        float wgt[16];
        int   off[16];
#pragma unroll
        for (int j = 0; j < 16; ++j) {
            const int c = 16 * sub + j;
            const bool cok = (c < TSEG);           // sub=3,j=15 -> col 63 unused
            const float t0 = tile[rr][c];
            const float t1 = tile[rr][(c < TSEG) ? c + 1 : c];
            const bool valid = cok && (t0 < INF) && (t1 < INF) && (t1 > t0);
            // tmid=0.5*(t0+t1); pts=a+tmid*d — separate f32 roundings, NO
            // FMA: asm pins the product (see header comment).
            const float tm = 0.5f * (t0 + t1);
            float mx = tm * dxx; asm volatile("" : "+v"(mx));
            float my = tm * dyy; asm volatile("" : "+v"(my));
            float mz = tm * dzz; asm volatile("" : "+v"(mz));
            const float px = ax + mx;
            const float py = ay + my;
            const float pz = az + mz;
            // clamp BEFORE int cast: inf/NaN -> well-defined OOB (fmaxf
            // returns the non-NaN operand on this HW; proven R5)
            const int ix = (int)floorf(fminf(fmaxf(px, -2.0f), 200.0f));
            const int iy = (int)floorf(fminf(fmaxf(py, -2.0f), 200.0f));
            const int iz = (int)floorf(fminf(fmaxf(pz, -2.0f), 200.0f));
            const bool inb = ((unsigned)ix < NXv) && ((unsigned)iy < NYv) && ((unsigned)iz < NZv);
            const int icx = min(max(ix, 0), NXv - 1);
            const int icy = min(max(iy, 0), NYv - 1);
            const int icz = min(max(iz, 0), NZv - 1);
            wgt[j] = (valid && inb) ? (t1 - t0) * raylen : 0.0f;
            off[j] = ((icx * NYv) + icy) * NZv + icz;
        }

        // --- phase B: ALL gathers back-to-back (32 in flight for BT=2) ---
        float g0[16], g1[16];
#pragma unroll
        for (int j = 0; j < 16; ++j) {
            g0[j] = vol[off[j]];
            if (BT > 1) g1[j] = vol[NVOX + off[j]];
        }

        // --- phase C: accumulate (same per-thread order as R8; +0 for
        //     invalid segments is exact) ---
#pragma unroll
        for (int j = 0; j < 16; ++j) {
            acc0 += wgt[j] * g0[j];
            if (BT > 1) acc1 += wgt[j] * g1[j];
        }

        __syncthreads();   // tile consumed; next iter may overwrite
    }

    // --- deterministic cross-sub reduction + coalesced write ---
    red[sub][rr][0] = acc0;
    red[sub][rr][1] = (BT > 1) ? acc1 : 0.0f;
    __syncthreads();
    if (sub == 0 && active) {
        const float s0v = red[0][rr][0] + red[1][rr][0] + red[2][rr][0] + red[3][rr][0];
        out[r] = s0v;
        if (BT > 1) {
            const float s1v = red[0][rr][1] + red[1][rr][1] + red[2][rr][1] + red[3][rr][1];
            out[R + r] = s1v;
        }
    }
}

extern "C" void kernel_launch(void* const* d_in, const int* in_sizes, int n_in,
                              void* d_out, int out_size, void* d_ws, size_t ws_size,
                              hipStream_t stream) {
    const float* vol   = (const float*)d_in[0];
    const float* tvals = (const float*)d_in[1];
    const float* Mm    = (const float*)d_in[2];
    const float* bb    = (const float*)d_in[3];
    const float* src   = (const float*)d_in[4];
    const float* dst   = (const float*)d_in[5];
    float* out = (float*)d_out;

    const int R = in_sizes[5] / 3;          // rays
    const int S = in_sizes[1] / R;          // t-values per ray
    const int B = in_sizes[0] / NVOX;       // batch of volumes

    const int blocks = (R + RPB - 1) / RPB;
    dim3 grid(blocks), block(256);

    if (B == 2) {
        ct_batch<2><<<grid, block, 0, stream>>>(vol, tvals, Mm, bb, src, dst, out, R, S);
    } else if (B == 1) {
        ct_batch<1><<<grid, block, 0, stream>>>(vol, tvals, Mm, bb, src, dst, out, R, S);
    } else {
        int c = 0;
        for (; c + 2 <= B; c += 2)
            ct_batch<2><<<grid, block, 0, stream>>>(vol + (long)c * NVOX, tvals, Mm, bb,
                                                    src, dst, out + (long)c * R, R, S);
        for (; c < B; ++c)
            ct_batch<1><<<grid, block, 0, stream>>>(vol + (long)c * NVOX, tvals, Mm, bb,
                                                    src, dst, out + (long)c * R, R, S);
    }
}

// Round 10
// 91.466 us; speedup vs baseline: 1.4589x; 1.4589x over previous
//
#include <hip/hip_runtime.h>
#include <math.h>

#define NXv 128
#define NYv 128
#define NZv 128
#define NVOX (NXv * NYv * NZv)
#define RPB  64    // rays per block (lane = ray in compute phase)
#define TSEG 63    // segments per LDS tile (loads TSEG+1 = 64 t-values/ray)

// Lane-per-ray tiled kernel + reg-prefetch pipeline + balanced ray remap (R10).
//  * tvals bits are AUTHORITATIVE: R6 proved on-the-fly recompute differs at
//    the ulp level (XLA divide != HW IEEE div bits) and flips knife-edge
//    floors. tvals must be read from memory.
//  * lane = ray (R7, 142->93us): adjacent rays differ only in detector v ->
//    volume gathers span few cache lines instead of 64 (R4/R5 floor).
//  * tvals coalescing via LDS transpose tile, stride 65 -> conflict-free.
//  * reg-prefetch of next tile before compute (R8, 93->84us).
//  * R9 FAILED (133us): 16-wide wgt/off/g0/g1 arrays spilled to scratch
//    (WRITE_SIZE 1->56MB) + unconditional gathers. Do not re-batch that wide.
//  * R10: static balance. Finite crossings per ray ~ 129+|u|+|v|; R8's
//    grid == exactly one residency round, so per-block work spread (2.4x)
//    showed up as 46% occupancy. |u|+|u+128| == 128 exactly for u<0, so
//    block b=(i,c) takes 32 rays from u-strip i (v-chunk c) and 32 from
//    strip i+256 -> per-block work nearly constant (v-term +-13%).
//
// NUMERICS (hard-won, rounds 1-9): x-segment midpoints land EXACTLY on
// floor() discontinuities. Golden ref is f32 numpy, SEPARATE mul-then-add.
// hipcc contracts a+tm*d into FMA -> absmax ~18.7 (threshold 1.25); __f*_rn
// are contractible (R2 == R1 bitwise); f64 mismatches (R3); recomputed t
// mismatches (R6). The asm VGPR pin on the product tm*d is what works
// (R4/R5/R7/R8 passed, absmax 0.0625). Do not remove. Keep contract(off).
template <int BT>
__global__ __launch_bounds__(256) void ct_bal(
    const float* __restrict__ vol,    // (B, NX, NY, NZ)
    const float* __restrict__ tvals,  // (R, S) sorted, +inf padded
    const float* __restrict__ Mm,     // (3,3)
    const float* __restrict__ bb,     // (3,)
    const float* __restrict__ src,    // (R,3)
    const float* __restrict__ dst,    // (R,3)
    float* __restrict__ out,          // (B, R)
    int R, int S, int remap)
{
#pragma clang fp contract(off)
    __shared__ float tile[RPB][TSEG + 2];   // 64 x 65: stride 65 -> conflict-free
    __shared__ float red[4][RPB][2];        // cross-sub reduction

    const float INF = __builtin_inff();
    const int t   = threadIdx.x;
    const int rr  = t & 63;        // compute role: ray slot within block
    const int sub = t >> 6;        // compute role: segment sub-range 0..3
    const int b   = blockIdx.x;

    // --- balanced slot->ray map: pair u-strip i with strip i+256 ---
    // slot<32: ray = i*256 + c*32 + slot ; slot>=32: ray = (i+256)*256 + c*32 + slot-32
    const int bi = b >> 3, bc = b & 7;
    auto ray_of = [&](int slot) -> int {
        if (remap)
            return ((bi + ((slot >> 5) << 8)) << 8) + (bc << 5) + (slot & 31);
        return b * RPB + slot;
    };
    const int r = ray_of(rr);
    const bool active = (r < R);

    // --- per-ray geometry (verified R4/R5/R7/R8) ---
    float ax = 0, ay = 0, az = 0, dxx = 0, dyy = 0, dzz = 0, raylen = 0;
    if (active) {
        const float sx = src[r * 3 + 0], sy = src[r * 3 + 1], sz = src[r * 3 + 2];
        const float ex = dst[r * 3 + 0], ey = dst[r * 3 + 1], ez = dst[r * 3 + 2];
        const float M00 = Mm[0], M01 = Mm[1], M02 = Mm[2];
        const float M10 = Mm[3], M11 = Mm[4], M12 = Mm[5];
        const float M20 = Mm[6], M21 = Mm[7], M22 = Mm[8];
        ax = M00 * sx + M01 * sy + M02 * sz + bb[0];
        ay = M10 * sx + M11 * sy + M12 * sz + bb[1];
        az = M20 * sx + M21 * sy + M22 * sz + bb[2];
        const float vx = ex - sx, vy = ey - sy, vz = ez - sz;
        dxx = M00 * vx + M01 * vy + M02 * vz;
        dyy = M10 * vx + M11 * vy + M12 * vz;
        dzz = M20 * vx + M21 * vy + M22 * vz;
        raylen = sqrtf(vx * vx + vy * vy + vz * vz);
    }

    const int nseg  = S - 1;
    const int ntile = (nseg + TSEG - 1) / TSEG;
    float acc0 = 0.0f, acc1 = 0.0f;

    // staged registers: pf[p] = tvals[ray_of(4p+sub)][s0 + rr]
    float pf[16];
    {
        const int idx = rr;                      // tile 0: s0 = 0
#pragma unroll
        for (int p = 0; p < 16; ++p) {
            const int ray = ray_of(p * 4 + sub);
            pf[p] = (ray < R && idx < S) ? tvals[(long)ray * S + idx] : INF;
        }
    }

    for (int tl = 0; tl < ntile; ++tl) {
        // --- stage-write: regs -> LDS (compiler inserts the vmcnt wait) ---
#pragma unroll
        for (int p = 0; p < 16; ++p)
            tile[p * 4 + sub][rr] = pf[p];

        // alive predicate from staged regs (tile-start values live in rr==0
        // threads): sorted + INF tail -> block-uniform break. The
        // syncthreads_count doubles as the write->read barrier.
        bool pred = false;
        if (rr == 0) {
#pragma unroll
            for (int p = 0; p < 16; ++p) pred |= (pf[p] < INF);
        }
        const int alive = __syncthreads_count(pred);
        if (alive == 0) break;

        // --- prefetch next tile into regs (issued; consumed next iter) ---
        if (tl + 1 < ntile) {
            const int idx = (tl + 1) * TSEG + rr;
#pragma unroll
            for (int p = 0; p < 16; ++p) {
                const int ray = ray_of(p * 4 + sub);
                pf[p] = (ray < R && idx < S) ? tvals[(long)ray * S + idx] : INF;
            }
        }

        // --- compute: thread (rr,sub) owns cols [16*sub, 16*sub+16), fully
        //     unrolled; s>=nseg needs no check (INF padding -> invalid) ---
        if (active) {
#pragma unroll
            for (int j = 0; j < 16; ++j) {
                const int c = 16 * sub + j;
                if (c < TSEG) {
                    const float t0 = tile[rr][c];
                    const float t1 = tile[rr][c + 1];
                    if ((t0 < INF) && (t1 < INF) && (t1 > t0)) {
                        // tmid=0.5*(t0+t1); pts=a+tmid*d — separate f32
                        // roundings, NO FMA: asm pins the product.
                        const float tm = 0.5f * (t0 + t1);
                        float mx = tm * dxx; asm volatile("" : "+v"(mx));
                        float my = tm * dyy; asm volatile("" : "+v"(my));
                        float mz = tm * dzz; asm volatile("" : "+v"(mz));
                        const float px = ax + mx;
                        const float py = ay + my;
                        const float pz = az + mz;
                        const int ix = (int)floorf(px);
                        const int iy = (int)floorf(py);
                        const int iz = (int)floorf(pz);
                        if ((unsigned)ix < NXv && (unsigned)iy < NYv && (unsigned)iz < NZv) {
                            const float w = (t1 - t0) * raylen;
                            const int flat = ((ix * NYv) + iy) * NZv + iz;
                            acc0 += w * vol[flat];
                            if (BT > 1) acc1 += w * vol[NVOX + flat];
                        }
                    }
                }
            }
        }
        __syncthreads();   // tile consumed; next iter may overwrite
    }

    // --- deterministic cross-sub reduction + write (32-lane coalesced runs) ---
    red[sub][rr][0] = acc0;
    red[sub][rr][1] = (BT > 1) ? acc1 : 0.0f;
    __syncthreads();
    if (sub == 0 && active) {
        const float s0v = red[0][rr][0] + red[1][rr][0] + red[2][rr][0] + red[3][rr][0];
        out[r] = s0v;
        if (BT > 1) {
            const float s1v = red[0][rr][1] + red[1][rr][1] + red[2][rr][1] + red[3][rr][1];
            out[R + r] = s1v;
        }
    }
}

extern "C" void kernel_launch(void* const* d_in, const int* in_sizes, int n_in,
                              void* d_out, int out_size, void* d_ws, size_t ws_size,
                              hipStream_t stream) {
    const float* vol   = (const float*)d_in[0];
    const float* tvals = (const float*)d_in[1];
    const float* Mm    = (const float*)d_in[2];
    const float* bb    = (const float*)d_in[3];
    const float* src   = (const float*)d_in[4];
    const float* dst   = (const float*)d_in[5];
    float* out = (float*)d_out;

    const int R = in_sizes[5] / 3;          // rays
    const int S = in_sizes[1] / R;          // t-values per ray
    const int B = in_sizes[0] / NVOX;       // batch of volumes

    // balanced remap assumes detector 512x256 (R = 131072, u-major)
    const int remap = (R == 512 * 256) ? 1 : 0;

    const int blocks = (R + RPB - 1) / RPB;
    dim3 grid(blocks), block(256);

    if (B == 2) {
        ct_bal<2><<<grid, block, 0, stream>>>(vol, tvals, Mm, bb, src, dst, out, R, S, remap);
    } else if (B == 1) {
        ct_bal<1><<<grid, block, 0, stream>>>(vol, tvals, Mm, bb, src, dst, out, R, S, remap);
    } else {
        int c = 0;
        for (; c + 2 <= B; c += 2)
            ct_bal<2><<<grid, block, 0, stream>>>(vol + (long)c * NVOX, tvals, Mm, bb,
                                                  src, dst, out + (long)c * R, R, S, remap);
        for (; c < B; ++c)
            ct_bal<1><<<grid, block, 0, stream>>>(vol + (long)c * NVOX, tvals, Mm, bb,
                                                  src, dst, out + (long)c * R, R, S, remap);
    }
}